// Round 9
// baseline (321.916 us; speedup 1.0000x reference)
//
#include <hip/hip_runtime.h>

#define IN_CH   128
#define OUT_CH  64
#define M_TILE  128         // nodes per block in the MFMA GEMM
#define XS_PITCH 136        // 128 bf16 + 8 pad (272 B row) -> conflict-free frags

typedef __attribute__((ext_vector_type(8))) short short8;
typedef __attribute__((ext_vector_type(4))) float floatx4;

__device__ __forceinline__ unsigned short f2bf(float f) {
    union { float f; unsigned u; } v; v.f = f;
    unsigned r = v.u + 0x7fffu + ((v.u >> 16) & 1u);   // RNE
    return (unsigned short)(r >> 16);
}
__device__ __forceinline__ float bfl(unsigned u) {   // low bf16 -> f32
    return __uint_as_float(u << 16);
}
__device__ __forceinline__ float bfh(unsigned u) {   // high bf16 -> f32
    return __uint_as_float(u & 0xffff0000u);
}

// ---------------------------------------------------------------------------
// Kernel 1 (prep): CSR rowptrs via edge-parallel diff scan + bf16 pre-pack of
// combined transposed weights WcT. R6 version verbatim (proven).
// ---------------------------------------------------------------------------
__global__ void prep_kernel(const int* __restrict__ tgtIn,
                            const int* __restrict__ tgtOut,
                            const float* __restrict__ Wmi,
                            const float* __restrict__ Wmo,
                            const float* __restrict__ Wsh,
                            int* __restrict__ rpIn,
                            int* __restrict__ rpOut,
                            unsigned short* __restrict__ WcT,
                            int n_nodes, int neIn, int neOut)
{
    int i = blockIdx.x * blockDim.x + threadIdx.x;
    const int nIn1 = neIn + 1, nOut1 = neOut + 1;

    if (i < nIn1 + nOut1) {
        const int* tgt; int* rp; int idx; int ne;
        if (i < nIn1) { tgt = tgtIn;  rp = rpIn;  idx = i;        ne = neIn; }
        else          { tgt = tgtOut; rp = rpOut; idx = i - nIn1; ne = neOut; }
        if (idx < ne) {
            int a    = tgt[idx];
            int prev = (idx == 0) ? -1 : tgt[idx - 1];
            for (int t = prev + 1; t <= a; ++t) rp[t] = idx;
        } else {
            int last = (ne > 0) ? tgt[ne - 1] : -1;
            for (int t = last + 1; t <= n_nodes; ++t) rp[t] = ne;
        }
    } else {
        int j = i - (nIn1 + nOut1);
        if (j < 2 * OUT_CH * IN_CH) {
            int n = j >> 7, k = j & 127;     // n: output col of Wc, k: input ch
            float m = (n < OUT_CH) ? Wmi[k * OUT_CH + n]
                                   : Wmo[k * OUT_CH + (n - OUT_CH)];
            float s = Wsh[k * OUT_CH + (n & (OUT_CH - 1))];
            WcT[n * IN_CH + k] = f2bf(m + s);
        }
    }
}

// ---------------------------------------------------------------------------
// Kernel 2 (MFMA GEMM): H = x_bf16 @ WcT^T. R6 version verbatim (best total).
// ---------------------------------------------------------------------------
__global__ __launch_bounds__(256, 3)
void gemm_kernel(const float* __restrict__ x,
                 const unsigned short* __restrict__ WcT,
                 unsigned short* __restrict__ Abf,
                 unsigned short* __restrict__ Bbf,
                 int n_nodes)
{
    __shared__ unsigned short Xs[M_TILE][XS_PITCH];   // 34.8 KB

    const int tid  = threadIdx.x;
    const int w    = tid >> 6;
    const int lane = tid & 63;
    const int l15  = lane & 15;
    const int quad = lane >> 4;
    const long long node0 = (long long)blockIdx.x * M_TILE;

    short8 bfrag[4][2];
#pragma unroll
    for (int ks = 0; ks < 4; ++ks)
#pragma unroll
        for (int ni = 0; ni < 2; ++ni)
            bfrag[ks][ni] = *(const short8*)&WcT[(w * 32 + ni * 16 + l15) * IN_CH
                                                 + ks * 32 + quad * 8];

    {
        const float4* x4 = (const float4*)x;
        for (int i = tid; i < M_TILE * (IN_CH / 4); i += 256) {
            int row = i >> 5, c4 = i & 31;
            long long node = node0 + row;
            float4 v = make_float4(0.f, 0.f, 0.f, 0.f);
            if (node < n_nodes) v = x4[node * (IN_CH / 4) + c4];
            uint2 p;
            p.x = ((unsigned)f2bf(v.y) << 16) | f2bf(v.x);
            p.y = ((unsigned)f2bf(v.w) << 16) | f2bf(v.z);
            *(uint2*)&Xs[row][c4 * 4] = p;
        }
    }
    __syncthreads();

    floatx4 acc[8][2];
#pragma unroll
    for (int mi = 0; mi < 8; ++mi)
#pragma unroll
        for (int ni = 0; ni < 2; ++ni)
            acc[mi][ni] = (floatx4){0.f, 0.f, 0.f, 0.f};

#pragma unroll
    for (int ks = 0; ks < 4; ++ks) {
        const int k0 = ks * 32 + quad * 8;
#pragma unroll
        for (int mi = 0; mi < 8; ++mi) {
            short8 a = *(const short8*)&Xs[mi * 16 + l15][k0];
            acc[mi][0] = __builtin_amdgcn_mfma_f32_16x16x32_bf16(a, bfrag[ks][0], acc[mi][0], 0, 0, 0);
            acc[mi][1] = __builtin_amdgcn_mfma_f32_16x16x32_bf16(a, bfrag[ks][1], acc[mi][1], 0, 0, 0);
        }
    }

    // ---- epilogue: acc -> LDS (bf16, full 128x128 tile), then coalesced out
    __syncthreads();                       // Xs reads done; safe to overwrite
    const int colb = w * 32;               // global col = w*32 + ni*16 + l15
#pragma unroll
    for (int mi = 0; mi < 8; ++mi)
#pragma unroll
        for (int ni = 0; ni < 2; ++ni)
#pragma unroll
            for (int r = 0; r < 4; ++r)
                Xs[mi * 16 + quad * 4 + r][colb + ni * 16 + l15] =
                    f2bf(acc[mi][ni][r]);
    __syncthreads();

    for (int i = tid; i < M_TILE * 16; i += 256) {
        int row  = i >> 4;
        int half = (i >> 3) & 1;
        int v4   = i & 7;
        long long node = node0 + row;
        if (node < n_nodes) {
            uint4 v = *(const uint4*)&Xs[row][half * 64 + v4 * 8];
            unsigned short* dst = half ? Bbf : Abf;
            *(uint4*)&dst[node * OUT_CH + v4 * 8] = v;
        }
    }
}

// ---------------------------------------------------------------------------
// Kernel 3: segmented weighted gather-sum + epilogue.
// R9: back to the ORIGINAL 1-deep pipeline (R0 structure, measured VGPR 48 --
// comfortably under the 64-VGPR / 8-waves-per-SIMD cliff) with
// __launch_bounds__(256, 8) to lift the occupancy cap. R8's spill disaster
// proved the memory system sustains 4.3 TB/s at 70% occupancy (vs 3.3 at
// 24%): aggregate outstanding gathers scale with resident waves. The 2-deep
// pipeline's +36 VGPRs (R1: 84) cost 4->8 waves of cap for only -3 us; this
// trades per-wave MLP back for wave count, with codegen the compiler has
// already proven it can fit without spills.
// ---------------------------------------------------------------------------
__global__ __launch_bounds__(256, 8)
void prop_kernel(const unsigned short* __restrict__ H,   // A base; B = A + Boff
                 const int* __restrict__ rpIn, const int* __restrict__ rpOut,
                 const int* __restrict__ srcIn, const float* __restrict__ ewIn,
                 const int* __restrict__ srcOut, const float* __restrict__ ewOut,
                 const float* __restrict__ bmi, const float* __restrict__ bmo,
                 const float* __restrict__ bsi, const float* __restrict__ bso,
                 const float* __restrict__ Cin, const float* __restrict__ Cout,
                 float* __restrict__ out, int n_nodes, int neIn, int neOut)
{
    const int lane = threadIdx.x & 63;
    const int wv   = threadIdx.x >> 6;
    const int e    = lane >> 3;           // eighth: which node of the eight
    const int el   = lane & 7;            // lane within eighth
    const int ch8  = el * 8;              // first of my 8 channels
    const int eb   = lane & 56;           // eighth base lane

    const unsigned short* Hq = H + ch8;   // per-lane channel-offset base

    const int t = ((int)blockIdx.x * 4 + wv) * 8 + e;
    const bool valid = (t < n_nodes);
    const int tc = valid ? t : 0;

    const int Boff = n_nodes * OUT_CH;    // element offset of B within H

    int ei0 = rpIn[tc],  ei1 = rpIn[tc + 1];
    int eo0 = rpOut[tc], eo1 = rpOut[tc + 1];
    int dIn  = ei1 - ei0;
    int len  = valid ? (dIn + (eo1 - eo0)) : 0;
    float ci = Cin[tc], co = Cout[tc];

    // Wave-uniform max combined length across the eight eighths (butterfly)
    int ml = len;
    ml = max(ml, __shfl_xor(ml, 8));
    ml = max(ml, __shfl_xor(ml, 16));
    ml = max(ml, __shfl_xor(ml, 32));
    const int maxlen = __builtin_amdgcn_readfirstlane(ml);

    float a0 = 0.f, a1 = 0.f, a2 = 0.f, a3 = 0.f;
    float a4 = 0.f, a5 = 0.f, a6 = 0.f, a7 = 0.f;

    // ---- raw pack loader: slot j of MY eighth's concatenated stream
    auto load_raw = [&](int j, int& sI, float& wI, int& sO, float& wO) {
        int iIn  = min(ei0 + max(0, min(j, dIn - 1)), neIn - 1);
        int jo   = j - dIn;
        int iOut = min(eo0 + max(0, jo), neOut - 1);
        sI = srcIn[iIn];  wI = ewIn[iIn];
        sO = srcOut[iOut]; wO = ewOut[iOut];
    };

    int   sI, sO;  float wI, wO;
    load_raw(el, sI, wI, sO, wO);       // pack 0

    for (int p = 0; p < maxlen; p += 8) {
        // ---- convert current raws to (rowb, wj)
        int j = p + el;
        bool inSeg  = (j < dIn);
        bool anySeg = (j < len);
        int   rowb = inSeg ? (sI * OUT_CH) : (sO * OUT_CH + Boff);
        rowb = anySeg ? rowb : 0;
        float wj = inSeg ? (ci * wI) : (anySeg ? (co * wO) : 0.f);

        // ---- prefetch next pack's raws (latency hidden by gather body)
        if (p + 8 < maxlen)
            load_raw(p + 8 + el, sI, wI, sO, wO);

        // ---- gather body: 8 slots, 8 uint4 gathers in flight (64 rows)
        int   r0 = __shfl(rowb, eb + 0), r1 = __shfl(rowb, eb + 1);
        int   r2 = __shfl(rowb, eb + 2), r3 = __shfl(rowb, eb + 3);
        int   r4 = __shfl(rowb, eb + 4), r5 = __shfl(rowb, eb + 5);
        int   r6 = __shfl(rowb, eb + 6), r7 = __shfl(rowb, eb + 7);
        float w0 = __shfl(wj, eb + 0), w1 = __shfl(wj, eb + 1);
        float w2 = __shfl(wj, eb + 2), w3 = __shfl(wj, eb + 3);
        float w4 = __shfl(wj, eb + 4), w5 = __shfl(wj, eb + 5);
        float w6 = __shfl(wj, eb + 6), w7 = __shfl(wj, eb + 7);
        uint4 u0 = *(const uint4*)(Hq + r0);
        uint4 u1 = *(const uint4*)(Hq + r1);
        uint4 u2 = *(const uint4*)(Hq + r2);
        uint4 u3 = *(const uint4*)(Hq + r3);
        uint4 u4 = *(const uint4*)(Hq + r4);
        uint4 u5 = *(const uint4*)(Hq + r5);
        uint4 u6 = *(const uint4*)(Hq + r6);
        uint4 u7 = *(const uint4*)(Hq + r7);
        // pad slots have w==0, row 0 -> safe no-ops
        a0 += w0 * bfl(u0.x); a1 += w0 * bfh(u0.x); a2 += w0 * bfl(u0.y); a3 += w0 * bfh(u0.y);
        a4 += w0 * bfl(u0.z); a5 += w0 * bfh(u0.z); a6 += w0 * bfl(u0.w); a7 += w0 * bfh(u0.w);
        a0 += w1 * bfl(u1.x); a1 += w1 * bfh(u1.x); a2 += w1 * bfl(u1.y); a3 += w1 * bfh(u1.y);
        a4 += w1 * bfl(u1.z); a5 += w1 * bfh(u1.z); a6 += w1 * bfl(u1.w); a7 += w1 * bfh(u1.w);
        a0 += w2 * bfl(u2.x); a1 += w2 * bfh(u2.x); a2 += w2 * bfl(u2.y); a3 += w2 * bfh(u2.y);
        a4 += w2 * bfl(u2.z); a5 += w2 * bfh(u2.z); a6 += w2 * bfl(u2.w); a7 += w2 * bfh(u2.w);
        a0 += w3 * bfl(u3.x); a1 += w3 * bfh(u3.x); a2 += w3 * bfl(u3.y); a3 += w3 * bfh(u3.y);
        a4 += w3 * bfl(u3.z); a5 += w3 * bfh(u3.z); a6 += w3 * bfl(u3.w); a7 += w3 * bfh(u3.w);
        a0 += w4 * bfl(u4.x); a1 += w4 * bfh(u4.x); a2 += w4 * bfl(u4.y); a3 += w4 * bfh(u4.y);
        a4 += w4 * bfl(u4.z); a5 += w4 * bfh(u4.z); a6 += w4 * bfl(u4.w); a7 += w4 * bfh(u4.w);
        a0 += w5 * bfl(u5.x); a1 += w5 * bfh(u5.x); a2 += w5 * bfl(u5.y); a3 += w5 * bfh(u5.y);
        a4 += w5 * bfl(u5.z); a5 += w5 * bfh(u5.z); a6 += w5 * bfl(u5.w); a7 += w5 * bfh(u5.w);
        a0 += w6 * bfl(u6.x); a1 += w6 * bfh(u6.x); a2 += w6 * bfl(u6.y); a3 += w6 * bfh(u6.y);
        a4 += w6 * bfl(u6.z); a5 += w6 * bfh(u6.z); a6 += w6 * bfl(u6.w); a7 += w6 * bfh(u6.w);
        a0 += w7 * bfl(u7.x); a1 += w7 * bfh(u7.x); a2 += w7 * bfl(u7.y); a3 += w7 * bfh(u7.y);
        a4 += w7 * bfl(u7.z); a5 += w7 * bfh(u7.z); a6 += w7 * bfl(u7.w); a7 += w7 * bfh(u7.w);
    }

    if (valid) {
        float4 o0, o1;
        o0.x = a0 + ci * (bmi[ch8 + 0] + bsi[ch8 + 0]) + co * (bmo[ch8 + 0] + bso[ch8 + 0]);
        o0.y = a1 + ci * (bmi[ch8 + 1] + bsi[ch8 + 1]) + co * (bmo[ch8 + 1] + bso[ch8 + 1]);
        o0.z = a2 + ci * (bmi[ch8 + 2] + bsi[ch8 + 2]) + co * (bmo[ch8 + 2] + bso[ch8 + 2]);
        o0.w = a3 + ci * (bmi[ch8 + 3] + bsi[ch8 + 3]) + co * (bmo[ch8 + 3] + bso[ch8 + 3]);
        o1.x = a4 + ci * (bmi[ch8 + 4] + bsi[ch8 + 4]) + co * (bmo[ch8 + 4] + bso[ch8 + 4]);
        o1.y = a5 + ci * (bmi[ch8 + 5] + bsi[ch8 + 5]) + co * (bmo[ch8 + 5] + bso[ch8 + 5]);
        o1.z = a6 + ci * (bmi[ch8 + 6] + bsi[ch8 + 6]) + co * (bmo[ch8 + 6] + bso[ch8 + 6]);
        o1.w = a7 + ci * (bmi[ch8 + 7] + bsi[ch8 + 7]) + co * (bmo[ch8 + 7] + bso[ch8 + 7]);
        float* ob = out + (long long)t * OUT_CH + ch8;
        *(float4*)ob = o0;
        *(float4*)(ob + 4) = o1;
    }
}

// ---------------------------------------------------------------------------
extern "C" void kernel_launch(void* const* d_in, const int* in_sizes, int n_in,
                              void* d_out, int out_size, void* d_ws, size_t ws_size,
                              hipStream_t stream)
{
    const float* x    = (const float*)d_in[0];
    const float* Wmi  = (const float*)d_in[1];
    const float* Wmo  = (const float*)d_in[2];
    const float* Wsh  = (const float*)d_in[3];
    const float* bmi  = (const float*)d_in[4];
    const float* bmo  = (const float*)d_in[5];
    const float* bsi  = (const float*)d_in[6];
    const float* bso  = (const float*)d_in[7];
    const float* Cin  = (const float*)d_in[8];
    const float* Cout = (const float*)d_in[9];
    const int*   eiIn  = (const int*)d_in[10];
    const float* ewIn  = (const float*)d_in[11];
    const int*   eiOut = (const int*)d_in[12];
    const float* ewOut = (const float*)d_in[13];

    const int n_nodes = in_sizes[0] / IN_CH;   // 100000
    const int neIn  = in_sizes[11];            // 1000000
    const int neOut = in_sizes[13];

    const int* srcIn  = eiIn;                  // edge_index[0]
    const int* tgtIn  = eiIn + neIn;           // edge_index[1] (sorted)
    const int* srcOut = eiOut;
    const int* tgtOut = eiOut + neOut;

    // Workspace layout: Abf|Bbf contiguous (bf16) | rpIn | rpOut | WcT (bf16)
    char* ws = (char*)d_ws;
    size_t NH = (size_t)n_nodes * OUT_CH * sizeof(unsigned short);
    unsigned short* Abf = (unsigned short*)ws;
    unsigned short* Bbf = (unsigned short*)(ws + NH);
    int* rpIn  = (int*)(ws + 2 * NH);
    int* rpOut = rpIn + (n_nodes + 1);
    unsigned short* WcT = (unsigned short*)(rpOut + (n_nodes + 1));

    // 1) rowptrs (edge-parallel diff scan) + combined-weight bf16 pre-pack
    int prep_threads = (neIn + 1) + (neOut + 1) + 2 * OUT_CH * IN_CH;
    prep_kernel<<<(prep_threads + 255) / 256, 256, 0, stream>>>(
        tgtIn, tgtOut, Wmi, Wmo, Wsh, rpIn, rpOut, WcT, n_nodes, neIn, neOut);

    // 2) fused dense transform via MFMA (N=128 GEMM: [A|B] columns)
    int gblocks = (n_nodes + M_TILE - 1) / M_TILE;
    gemm_kernel<<<gblocks, 256, 0, stream>>>(x, WcT, Abf, Bbf, n_nodes);

    // 3) segmented gather-sum + epilogue (1-deep pipeline, 8 waves/SIMD cap)
    int pblocks = (n_nodes + 31) / 32;         // 32 nodes per block
    prop_kernel<<<pblocks, 256, 0, stream>>>(
        Abf, rpIn, rpOut, srcIn, ewIn, srcOut, ewOut,
        bmi, bmo, bsi, bso, Cin, Cout, (float*)d_out, n_nodes, neIn, neOut);
}

// Round 10
// 183.795 us; speedup vs baseline: 1.7515x; 1.7515x over previous
//
#include <hip/hip_runtime.h>

#define IN_CH   128
#define OUT_CH  64
#define M_TILE  128         // nodes per block in the MFMA GEMM
#define XS_PITCH 136        // 128 bf16 + 8 pad (272 B row) -> conflict-free frags

typedef __attribute__((ext_vector_type(8))) short short8;
typedef __attribute__((ext_vector_type(4))) float floatx4;

__device__ __forceinline__ unsigned short f2bf(float f) {
    union { float f; unsigned u; } v; v.f = f;
    unsigned r = v.u + 0x7fffu + ((v.u >> 16) & 1u);   // RNE
    return (unsigned short)(r >> 16);
}
__device__ __forceinline__ float bfl(unsigned u) {   // low bf16 -> f32
    return __uint_as_float(u << 16);
}
__device__ __forceinline__ float bfh(unsigned u) {   // high bf16 -> f32
    return __uint_as_float(u & 0xffff0000u);
}

// ---------------------------------------------------------------------------
// Kernel 1 (prep): CSR rowptrs via edge-parallel diff scan + bf16 pre-pack of
// combined transposed weights WcT. R6 version verbatim (proven).
// ---------------------------------------------------------------------------
__global__ void prep_kernel(const int* __restrict__ tgtIn,
                            const int* __restrict__ tgtOut,
                            const float* __restrict__ Wmi,
                            const float* __restrict__ Wmo,
                            const float* __restrict__ Wsh,
                            int* __restrict__ rpIn,
                            int* __restrict__ rpOut,
                            unsigned short* __restrict__ WcT,
                            int n_nodes, int neIn, int neOut)
{
    int i = blockIdx.x * blockDim.x + threadIdx.x;
    const int nIn1 = neIn + 1, nOut1 = neOut + 1;

    if (i < nIn1 + nOut1) {
        const int* tgt; int* rp; int idx; int ne;
        if (i < nIn1) { tgt = tgtIn;  rp = rpIn;  idx = i;        ne = neIn; }
        else          { tgt = tgtOut; rp = rpOut; idx = i - nIn1; ne = neOut; }
        if (idx < ne) {
            int a    = tgt[idx];
            int prev = (idx == 0) ? -1 : tgt[idx - 1];
            for (int t = prev + 1; t <= a; ++t) rp[t] = idx;
        } else {
            int last = (ne > 0) ? tgt[ne - 1] : -1;
            for (int t = last + 1; t <= n_nodes; ++t) rp[t] = ne;
        }
    } else {
        int j = i - (nIn1 + nOut1);
        if (j < 2 * OUT_CH * IN_CH) {
            int n = j >> 7, k = j & 127;     // n: output col of Wc, k: input ch
            float m = (n < OUT_CH) ? Wmi[k * OUT_CH + n]
                                   : Wmo[k * OUT_CH + (n - OUT_CH)];
            float s = Wsh[k * OUT_CH + (n & (OUT_CH - 1))];
            WcT[n * IN_CH + k] = f2bf(m + s);
        }
    }
}

// ---------------------------------------------------------------------------
// Kernel 2 (MFMA GEMM): H = x_bf16 @ WcT^T. R6 version verbatim (best total).
// ---------------------------------------------------------------------------
__global__ __launch_bounds__(256, 3)
void gemm_kernel(const float* __restrict__ x,
                 const unsigned short* __restrict__ WcT,
                 unsigned short* __restrict__ Abf,
                 unsigned short* __restrict__ Bbf,
                 int n_nodes)
{
    __shared__ unsigned short Xs[M_TILE][XS_PITCH];   // 34.8 KB

    const int tid  = threadIdx.x;
    const int w    = tid >> 6;
    const int lane = tid & 63;
    const int l15  = lane & 15;
    const int quad = lane >> 4;
    const long long node0 = (long long)blockIdx.x * M_TILE;

    short8 bfrag[4][2];
#pragma unroll
    for (int ks = 0; ks < 4; ++ks)
#pragma unroll
        for (int ni = 0; ni < 2; ++ni)
            bfrag[ks][ni] = *(const short8*)&WcT[(w * 32 + ni * 16 + l15) * IN_CH
                                                 + ks * 32 + quad * 8];

    {
        const float4* x4 = (const float4*)x;
        for (int i = tid; i < M_TILE * (IN_CH / 4); i += 256) {
            int row = i >> 5, c4 = i & 31;
            long long node = node0 + row;
            float4 v = make_float4(0.f, 0.f, 0.f, 0.f);
            if (node < n_nodes) v = x4[node * (IN_CH / 4) + c4];
            uint2 p;
            p.x = ((unsigned)f2bf(v.y) << 16) | f2bf(v.x);
            p.y = ((unsigned)f2bf(v.w) << 16) | f2bf(v.z);
            *(uint2*)&Xs[row][c4 * 4] = p;
        }
    }
    __syncthreads();

    floatx4 acc[8][2];
#pragma unroll
    for (int mi = 0; mi < 8; ++mi)
#pragma unroll
        for (int ni = 0; ni < 2; ++ni)
            acc[mi][ni] = (floatx4){0.f, 0.f, 0.f, 0.f};

#pragma unroll
    for (int ks = 0; ks < 4; ++ks) {
        const int k0 = ks * 32 + quad * 8;
#pragma unroll
        for (int mi = 0; mi < 8; ++mi) {
            short8 a = *(const short8*)&Xs[mi * 16 + l15][k0];
            acc[mi][0] = __builtin_amdgcn_mfma_f32_16x16x32_bf16(a, bfrag[ks][0], acc[mi][0], 0, 0, 0);
            acc[mi][1] = __builtin_amdgcn_mfma_f32_16x16x32_bf16(a, bfrag[ks][1], acc[mi][1], 0, 0, 0);
        }
    }

    // ---- epilogue: acc -> LDS (bf16, full 128x128 tile), then coalesced out
    __syncthreads();                       // Xs reads done; safe to overwrite
    const int colb = w * 32;               // global col = w*32 + ni*16 + l15
#pragma unroll
    for (int mi = 0; mi < 8; ++mi)
#pragma unroll
        for (int ni = 0; ni < 2; ++ni)
#pragma unroll
            for (int r = 0; r < 4; ++r)
                Xs[mi * 16 + quad * 4 + r][colb + ni * 16 + l15] =
                    f2bf(acc[mi][ni][r]);
    __syncthreads();

    for (int i = tid; i < M_TILE * 16; i += 256) {
        int row  = i >> 4;
        int half = (i >> 3) & 1;
        int v4   = i & 7;
        long long node = node0 + row;
        if (node < n_nodes) {
            uint4 v = *(const uint4*)&Xs[row][half * 64 + v4 * 8];
            unsigned short* dst = half ? Bbf : Abf;
            *(uint4*)&dst[node * OUT_CH + v4 * 8] = v;
        }
    }
}

// ---------------------------------------------------------------------------
// Kernel 3: segmented weighted gather-sum + epilogue.
// R10: multi-group waves with cross-group metadata prefetch. Diagnosis from
// R6 numbers: each wave had ONE 8-node group = only ~4 pack-iterations, so
// the serial startup chain (rp load -> C load -> edge load -> gather, 3-4
// dependent latencies ~2000 cy) dominated the ~4100 cy/pack wall time.
// Now 4096 waves (1024 blocks) grid-stride over ~3 groups each; the NEXT
// group's rp/C loads are issued right after the current group's first edge
// load, so groups 2..N start with metadata already in registers. Pack body
// is the proven R0 1-deep pipeline (lowest-VGPR variant). Biases hoisted
// per-wave. NO min-waves launch bound (R8/R9: forcing 8 waves/SIMD spills).
// Math is bit-identical to R6.
// ---------------------------------------------------------------------------
__global__ __launch_bounds__(256)
void prop_kernel(const unsigned short* __restrict__ H,   // A base; B = A + Boff
                 const int* __restrict__ rpIn, const int* __restrict__ rpOut,
                 const int* __restrict__ srcIn, const float* __restrict__ ewIn,
                 const int* __restrict__ srcOut, const float* __restrict__ ewOut,
                 const float* __restrict__ bmi, const float* __restrict__ bmo,
                 const float* __restrict__ bsi, const float* __restrict__ bso,
                 const float* __restrict__ Cin, const float* __restrict__ Cout,
                 float* __restrict__ out, int n_nodes, int neIn, int neOut,
                 int ngroups)
{
    const int lane = threadIdx.x & 63;
    const int wv   = threadIdx.x >> 6;
    const int e    = lane >> 3;           // eighth: which node of the eight
    const int el   = lane & 7;            // lane within eighth
    const int ch8  = el * 8;              // first of my 8 channels
    const int eb   = lane & 56;           // eighth base lane

    const unsigned short* Hq = H + ch8;   // per-lane channel-offset base
    const int Boff = n_nodes * OUT_CH;    // element offset of B within H

    // hoisted combined biases for my 8 channels (L2-hot, once per wave)
    float bI[8], bO[8];
#pragma unroll
    for (int k = 0; k < 8; ++k) {
        bI[k] = bmi[ch8 + k] + bsi[ch8 + k];
        bO[k] = bmo[ch8 + k] + bso[ch8 + k];
    }

    const int wid  = (int)blockIdx.x * 4 + wv;   // wave id
    const int wstr = (int)gridDim.x * 4;         // total waves

    // next-group metadata (prefetched; in flight across current group's packs)
    int   tn = 0, ei0n = 0, ei1n = 0, eo0n = 0, eo1n = 0;
    float cin = 0.f, con = 0.f;
    bool  vn = false;

    auto meta = [&](int g) {
        tn = g * 8 + e;
        vn = (tn < n_nodes);
        int tcl = vn ? tn : 0;
        ei0n = rpIn[tcl];  ei1n = rpIn[tcl + 1];
        eo0n = rpOut[tcl]; eo1n = rpOut[tcl + 1];
        cin  = Cin[tcl];   con  = Cout[tcl];
    };

    if (wid < ngroups) meta(wid);

    for (int g = wid; g < ngroups; g += wstr) {
        // ---- adopt prefetched metadata for this group
        const int   t     = tn;
        const bool  valid = vn;
        const int   ei0   = ei0n, eo0 = eo0n;
        const int   dIn   = ei1n - ei0n;
        const int   len   = valid ? (dIn + (eo1n - eo0n)) : 0;
        const float ci    = cin, co = con;

        // wave-uniform max combined length across the eight eighths
        int ml = len;
        ml = max(ml, __shfl_xor(ml, 8));
        ml = max(ml, __shfl_xor(ml, 16));
        ml = max(ml, __shfl_xor(ml, 32));
        const int maxlen = __builtin_amdgcn_readfirstlane(ml);

        // raw pack loader: slot j of MY eighth's concatenated stream
        auto load_raw = [&](int j, int& sI, float& wI, int& sO, float& wO) {
            int iIn  = min(ei0 + max(0, min(j, dIn - 1)), neIn - 1);
            int jo   = j - dIn;
            int iOut = min(eo0 + max(0, jo), neOut - 1);
            sI = srcIn[iIn];  wI = ewIn[iIn];
            sO = srcOut[iOut]; wO = ewOut[iOut];
        };

        int sI, sO; float wI, wO;
        load_raw(el, sI, wI, sO, wO);        // pack 0 edges in flight

        // ---- prefetch NEXT group's metadata (hidden under this group's body)
        if (g + wstr < ngroups) meta(g + wstr);

        float a0 = 0.f, a1 = 0.f, a2 = 0.f, a3 = 0.f;
        float a4 = 0.f, a5 = 0.f, a6 = 0.f, a7 = 0.f;

        for (int p = 0; p < maxlen; p += 8) {
            // convert current raws to (rowb, wj)
            int j = p + el;
            bool inSeg  = (j < dIn);
            bool anySeg = (j < len);
            int   rowb = inSeg ? (sI * OUT_CH) : (sO * OUT_CH + Boff);
            rowb = anySeg ? rowb : 0;
            float wj = inSeg ? (ci * wI) : (anySeg ? (co * wO) : 0.f);

            // prefetch next pack's raws (latency hidden by gather body)
            if (p + 8 < maxlen)
                load_raw(p + 8 + el, sI, wI, sO, wO);

            // gather body: 8 slots, 8 uint4 gathers in flight (64 rows)
            int   r0 = __shfl(rowb, eb + 0), r1 = __shfl(rowb, eb + 1);
            int   r2 = __shfl(rowb, eb + 2), r3 = __shfl(rowb, eb + 3);
            int   r4 = __shfl(rowb, eb + 4), r5 = __shfl(rowb, eb + 5);
            int   r6 = __shfl(rowb, eb + 6), r7 = __shfl(rowb, eb + 7);
            float w0 = __shfl(wj, eb + 0), w1 = __shfl(wj, eb + 1);
            float w2 = __shfl(wj, eb + 2), w3 = __shfl(wj, eb + 3);
            float w4 = __shfl(wj, eb + 4), w5 = __shfl(wj, eb + 5);
            float w6 = __shfl(wj, eb + 6), w7 = __shfl(wj, eb + 7);
            uint4 u0 = *(const uint4*)(Hq + r0);
            uint4 u1 = *(const uint4*)(Hq + r1);
            uint4 u2 = *(const uint4*)(Hq + r2);
            uint4 u3 = *(const uint4*)(Hq + r3);
            uint4 u4 = *(const uint4*)(Hq + r4);
            uint4 u5 = *(const uint4*)(Hq + r5);
            uint4 u6 = *(const uint4*)(Hq + r6);
            uint4 u7 = *(const uint4*)(Hq + r7);
            // pad slots have w==0, row 0 -> safe no-ops
            a0 += w0 * bfl(u0.x); a1 += w0 * bfh(u0.x); a2 += w0 * bfl(u0.y); a3 += w0 * bfh(u0.y);
            a4 += w0 * bfl(u0.z); a5 += w0 * bfh(u0.z); a6 += w0 * bfl(u0.w); a7 += w0 * bfh(u0.w);
            a0 += w1 * bfl(u1.x); a1 += w1 * bfh(u1.x); a2 += w1 * bfl(u1.y); a3 += w1 * bfh(u1.y);
            a4 += w1 * bfl(u1.z); a5 += w1 * bfh(u1.z); a6 += w1 * bfl(u1.w); a7 += w1 * bfh(u1.w);
            a0 += w2 * bfl(u2.x); a1 += w2 * bfh(u2.x); a2 += w2 * bfl(u2.y); a3 += w2 * bfh(u2.y);
            a4 += w2 * bfl(u2.z); a5 += w2 * bfh(u2.z); a6 += w2 * bfl(u2.w); a7 += w2 * bfh(u2.w);
            a0 += w3 * bfl(u3.x); a1 += w3 * bfh(u3.x); a2 += w3 * bfl(u3.y); a3 += w3 * bfh(u3.y);
            a4 += w3 * bfl(u3.z); a5 += w3 * bfh(u3.z); a6 += w3 * bfl(u3.w); a7 += w3 * bfh(u3.w);
            a0 += w4 * bfl(u4.x); a1 += w4 * bfh(u4.x); a2 += w4 * bfl(u4.y); a3 += w4 * bfh(u4.y);
            a4 += w4 * bfl(u4.z); a5 += w4 * bfh(u4.z); a6 += w4 * bfl(u4.w); a7 += w4 * bfh(u4.w);
            a0 += w5 * bfl(u5.x); a1 += w5 * bfh(u5.x); a2 += w5 * bfl(u5.y); a3 += w5 * bfh(u5.y);
            a4 += w5 * bfl(u5.z); a5 += w5 * bfh(u5.z); a6 += w5 * bfl(u5.w); a7 += w5 * bfh(u5.w);
            a0 += w6 * bfl(u6.x); a1 += w6 * bfh(u6.x); a2 += w6 * bfl(u6.y); a3 += w6 * bfh(u6.y);
            a4 += w6 * bfl(u6.z); a5 += w6 * bfh(u6.z); a6 += w6 * bfl(u6.w); a7 += w6 * bfh(u6.w);
            a0 += w7 * bfl(u7.x); a1 += w7 * bfh(u7.x); a2 += w7 * bfl(u7.y); a3 += w7 * bfh(u7.y);
            a4 += w7 * bfl(u7.z); a5 += w7 * bfh(u7.z); a6 += w7 * bfl(u7.w); a7 += w7 * bfh(u7.w);
        }

        if (valid) {
            float4 o0, o1;
            o0.x = a0 + ci * bI[0] + co * bO[0];
            o0.y = a1 + ci * bI[1] + co * bO[1];
            o0.z = a2 + ci * bI[2] + co * bO[2];
            o0.w = a3 + ci * bI[3] + co * bO[3];
            o1.x = a4 + ci * bI[4] + co * bO[4];
            o1.y = a5 + ci * bI[5] + co * bO[5];
            o1.z = a6 + ci * bI[6] + co * bO[6];
            o1.w = a7 + ci * bI[7] + co * bO[7];
            float* ob = out + (long long)t * OUT_CH + ch8;
            *(float4*)ob = o0;
            *(float4*)(ob + 4) = o1;
        }
    }
}

// ---------------------------------------------------------------------------
extern "C" void kernel_launch(void* const* d_in, const int* in_sizes, int n_in,
                              void* d_out, int out_size, void* d_ws, size_t ws_size,
                              hipStream_t stream)
{
    const float* x    = (const float*)d_in[0];
    const float* Wmi  = (const float*)d_in[1];
    const float* Wmo  = (const float*)d_in[2];
    const float* Wsh  = (const float*)d_in[3];
    const float* bmi  = (const float*)d_in[4];
    const float* bmo  = (const float*)d_in[5];
    const float* bsi  = (const float*)d_in[6];
    const float* bso  = (const float*)d_in[7];
    const float* Cin  = (const float*)d_in[8];
    const float* Cout = (const float*)d_in[9];
    const int*   eiIn  = (const int*)d_in[10];
    const float* ewIn  = (const float*)d_in[11];
    const int*   eiOut = (const int*)d_in[12];
    const float* ewOut = (const float*)d_in[13];

    const int n_nodes = in_sizes[0] / IN_CH;   // 100000
    const int neIn  = in_sizes[11];            // 1000000
    const int neOut = in_sizes[13];

    const int* srcIn  = eiIn;                  // edge_index[0]
    const int* tgtIn  = eiIn + neIn;           // edge_index[1] (sorted)
    const int* srcOut = eiOut;
    const int* tgtOut = eiOut + neOut;

    // Workspace layout: Abf|Bbf contiguous (bf16) | rpIn | rpOut | WcT (bf16)
    char* ws = (char*)d_ws;
    size_t NH = (size_t)n_nodes * OUT_CH * sizeof(unsigned short);
    unsigned short* Abf = (unsigned short*)ws;
    unsigned short* Bbf = (unsigned short*)(ws + NH);
    int* rpIn  = (int*)(ws + 2 * NH);
    int* rpOut = rpIn + (n_nodes + 1);
    unsigned short* WcT = (unsigned short*)(rpOut + (n_nodes + 1));

    // 1) rowptrs (edge-parallel diff scan) + combined-weight bf16 pre-pack
    int prep_threads = (neIn + 1) + (neOut + 1) + 2 * OUT_CH * IN_CH;
    prep_kernel<<<(prep_threads + 255) / 256, 256, 0, stream>>>(
        tgtIn, tgtOut, Wmi, Wmo, Wsh, rpIn, rpOut, WcT, n_nodes, neIn, neOut);

    // 2) fused dense transform via MFMA (N=128 GEMM: [A|B] columns)
    int gblocks = (n_nodes + M_TILE - 1) / M_TILE;
    gemm_kernel<<<gblocks, 256, 0, stream>>>(x, WcT, Abf, Bbf, n_nodes);

    // 3) segmented gather-sum + epilogue (multi-group waves, meta prefetch)
    int ngroups = (n_nodes + 7) / 8;           // 12500 node-groups
    int pblocks = 1024;                        // 4096 waves, ~3 groups each
    if (pblocks * 4 > ngroups) pblocks = (ngroups + 3) / 4;
    prop_kernel<<<pblocks, 256, 0, stream>>>(
        Abf, rpIn, rpOut, srcIn, ewIn, srcOut, ewOut,
        bmi, bmo, bsi, bso, Cin, Cout, (float*)d_out, n_nodes, neIn, neOut,
        ngroups);
}

// Round 11
// 175.222 us; speedup vs baseline: 1.8372x; 1.0489x over previous
//
#include <hip/hip_runtime.h>

#define IN_CH   128
#define OUT_CH  64
#define M_TILE  128         // nodes per block in the MFMA GEMM
#define XS_PITCH 136        // 128 bf16 + 8 pad (272 B row) -> conflict-free frags

typedef __attribute__((ext_vector_type(8))) short short8;
typedef __attribute__((ext_vector_type(4))) float floatx4;

__device__ __forceinline__ unsigned short f2bf(float f) {
    union { float f; unsigned u; } v; v.f = f;
    unsigned r = v.u + 0x7fffu + ((v.u >> 16) & 1u);   // RNE
    return (unsigned short)(r >> 16);
}
__device__ __forceinline__ float bfl(unsigned u) {   // low bf16 -> f32
    return __uint_as_float(u << 16);
}
__device__ __forceinline__ float bfh(unsigned u) {   // high bf16 -> f32
    return __uint_as_float(u & 0xffff0000u);
}

// ---------------------------------------------------------------------------
// Kernel 1 (prep): CSR rowptrs via edge-parallel diff scan + bf16 pre-pack of
// combined transposed weights WcT. R6 version verbatim (proven best).
// ---------------------------------------------------------------------------
__global__ void prep_kernel(const int* __restrict__ tgtIn,
                            const int* __restrict__ tgtOut,
                            const float* __restrict__ Wmi,
                            const float* __restrict__ Wmo,
                            const float* __restrict__ Wsh,
                            int* __restrict__ rpIn,
                            int* __restrict__ rpOut,
                            unsigned short* __restrict__ WcT,
                            int n_nodes, int neIn, int neOut)
{
    int i = blockIdx.x * blockDim.x + threadIdx.x;
    const int nIn1 = neIn + 1, nOut1 = neOut + 1;

    if (i < nIn1 + nOut1) {
        const int* tgt; int* rp; int idx; int ne;
        if (i < nIn1) { tgt = tgtIn;  rp = rpIn;  idx = i;        ne = neIn; }
        else          { tgt = tgtOut; rp = rpOut; idx = i - nIn1; ne = neOut; }
        if (idx < ne) {
            int a    = tgt[idx];
            int prev = (idx == 0) ? -1 : tgt[idx - 1];
            for (int t = prev + 1; t <= a; ++t) rp[t] = idx;
        } else {
            int last = (ne > 0) ? tgt[ne - 1] : -1;
            for (int t = last + 1; t <= n_nodes; ++t) rp[t] = ne;
        }
    } else {
        int j = i - (nIn1 + nOut1);
        if (j < 2 * OUT_CH * IN_CH) {
            int n = j >> 7, k = j & 127;     // n: output col of Wc, k: input ch
            float m = (n < OUT_CH) ? Wmi[k * OUT_CH + n]
                                   : Wmo[k * OUT_CH + (n - OUT_CH)];
            float s = Wsh[k * OUT_CH + (n & (OUT_CH - 1))];
            WcT[n * IN_CH + k] = f2bf(m + s);
        }
    }
}

// ---------------------------------------------------------------------------
// Kernel 2 (MFMA GEMM): H = x_bf16 @ WcT^T. R6 structure; R11 adds a
// wave-uniform FULL-TILE fast path (781/782 blocks) dropping per-row bounds
// checks in x-staging and the C-store loop. Tail block takes the original
// checked path — behavior identical.
// ---------------------------------------------------------------------------
__global__ __launch_bounds__(256, 3)
void gemm_kernel(const float* __restrict__ x,
                 const unsigned short* __restrict__ WcT,
                 unsigned short* __restrict__ Abf,
                 unsigned short* __restrict__ Bbf,
                 int n_nodes)
{
    __shared__ unsigned short Xs[M_TILE][XS_PITCH];   // 34.8 KB

    const int tid  = threadIdx.x;
    const int w    = tid >> 6;
    const int lane = tid & 63;
    const int l15  = lane & 15;
    const int quad = lane >> 4;
    const long long node0 = (long long)blockIdx.x * M_TILE;
    const bool fullTile = (node0 + M_TILE) <= (long long)n_nodes;

    short8 bfrag[4][2];
#pragma unroll
    for (int ks = 0; ks < 4; ++ks)
#pragma unroll
        for (int ni = 0; ni < 2; ++ni)
            bfrag[ks][ni] = *(const short8*)&WcT[(w * 32 + ni * 16 + l15) * IN_CH
                                                 + ks * 32 + quad * 8];

    {
        const float4* x4 = (const float4*)x;
        if (fullTile) {
            for (int i = tid; i < M_TILE * (IN_CH / 4); i += 256) {
                int row = i >> 5, c4 = i & 31;
                float4 v = x4[(node0 + row) * (IN_CH / 4) + c4];
                uint2 p;
                p.x = ((unsigned)f2bf(v.y) << 16) | f2bf(v.x);
                p.y = ((unsigned)f2bf(v.w) << 16) | f2bf(v.z);
                *(uint2*)&Xs[row][c4 * 4] = p;
            }
        } else {
            for (int i = tid; i < M_TILE * (IN_CH / 4); i += 256) {
                int row = i >> 5, c4 = i & 31;
                long long node = node0 + row;
                float4 v = make_float4(0.f, 0.f, 0.f, 0.f);
                if (node < n_nodes) v = x4[node * (IN_CH / 4) + c4];
                uint2 p;
                p.x = ((unsigned)f2bf(v.y) << 16) | f2bf(v.x);
                p.y = ((unsigned)f2bf(v.w) << 16) | f2bf(v.z);
                *(uint2*)&Xs[row][c4 * 4] = p;
            }
        }
    }
    __syncthreads();

    floatx4 acc[8][2];
#pragma unroll
    for (int mi = 0; mi < 8; ++mi)
#pragma unroll
        for (int ni = 0; ni < 2; ++ni)
            acc[mi][ni] = (floatx4){0.f, 0.f, 0.f, 0.f};

#pragma unroll
    for (int ks = 0; ks < 4; ++ks) {
        const int k0 = ks * 32 + quad * 8;
#pragma unroll
        for (int mi = 0; mi < 8; ++mi) {
            short8 a = *(const short8*)&Xs[mi * 16 + l15][k0];
            acc[mi][0] = __builtin_amdgcn_mfma_f32_16x16x32_bf16(a, bfrag[ks][0], acc[mi][0], 0, 0, 0);
            acc[mi][1] = __builtin_amdgcn_mfma_f32_16x16x32_bf16(a, bfrag[ks][1], acc[mi][1], 0, 0, 0);
        }
    }

    // ---- epilogue: acc -> LDS (bf16, full 128x128 tile), then coalesced out
    __syncthreads();                       // Xs reads done; safe to overwrite
    const int colb = w * 32;               // global col = w*32 + ni*16 + l15
#pragma unroll
    for (int mi = 0; mi < 8; ++mi)
#pragma unroll
        for (int ni = 0; ni < 2; ++ni)
#pragma unroll
            for (int r = 0; r < 4; ++r)
                Xs[mi * 16 + quad * 4 + r][colb + ni * 16 + l15] =
                    f2bf(acc[mi][ni][r]);
    __syncthreads();

    if (fullTile) {
        for (int i = tid; i < M_TILE * 16; i += 256) {
            int row  = i >> 4;
            int half = (i >> 3) & 1;
            int v4   = i & 7;
            uint4 v = *(const uint4*)&Xs[row][half * 64 + v4 * 8];
            unsigned short* dst = half ? Bbf : Abf;
            *(uint4*)&dst[(node0 + row) * OUT_CH + v4 * 8] = v;
        }
    } else {
        for (int i = tid; i < M_TILE * 16; i += 256) {
            int row  = i >> 4;
            int half = (i >> 3) & 1;
            int v4   = i & 7;
            long long node = node0 + row;
            if (node < n_nodes) {
                uint4 v = *(const uint4*)&Xs[row][half * 64 + v4 * 8];
                unsigned short* dst = half ? Bbf : Abf;
                *(uint4*)&dst[node * OUT_CH + v4 * 8] = v;
            }
        }
    }
}

// ---------------------------------------------------------------------------
// Kernel 3: segmented weighted gather-sum + epilogue.
// R6 version VERBATIM (best measured: 43.5 us). Plateau evidence: five
// structurally distinct variants (1-deep/41% occ, 2-deep/24%, 1-wave blocks,
// multi-group prefetch/33%, sorted orders) all land 43-47 us. Real gather
// traffic 2.05M x 128 B = 262 MB / 43.5 us ~= 10 B/cy/CU = the measured
// HBM-class per-CU load service rate (H working set 25.6 MB >> 4 MB per-XCD
// L2 -> gathers are L2-miss dominated). prop is at its traffic floor.
// ---------------------------------------------------------------------------
__global__ __launch_bounds__(256)
void prop_kernel(const unsigned short* __restrict__ H,   // A base; B = A + Boff
                 const int* __restrict__ rpIn, const int* __restrict__ rpOut,
                 const int* __restrict__ srcIn, const float* __restrict__ ewIn,
                 const int* __restrict__ srcOut, const float* __restrict__ ewOut,
                 const float* __restrict__ bmi, const float* __restrict__ bmo,
                 const float* __restrict__ bsi, const float* __restrict__ bso,
                 const float* __restrict__ Cin, const float* __restrict__ Cout,
                 float* __restrict__ out, int n_nodes, int neIn, int neOut)
{
    const int lane = threadIdx.x & 63;
    const int wv   = threadIdx.x >> 6;
    const int e    = lane >> 3;           // eighth: which node of the eight
    const int el   = lane & 7;            // lane within eighth
    const int ch8  = el * 8;              // first of my 8 channels
    const int eb   = lane & 56;           // eighth base lane

    const unsigned short* Hq = H + ch8;   // per-lane channel-offset base

    const int t = ((int)blockIdx.x * 4 + wv) * 8 + e;
    const bool valid = (t < n_nodes);
    const int tc = valid ? t : 0;

    const int Boff = n_nodes * OUT_CH;    // element offset of B within H

    int ei0 = rpIn[tc],  ei1 = rpIn[tc + 1];
    int eo0 = rpOut[tc], eo1 = rpOut[tc + 1];
    int dIn  = ei1 - ei0;
    int len  = valid ? (dIn + (eo1 - eo0)) : 0;
    float ci = Cin[tc], co = Cout[tc];

    // Wave-uniform max combined length across the eight eighths (butterfly)
    int ml = len;
    ml = max(ml, __shfl_xor(ml, 8));
    ml = max(ml, __shfl_xor(ml, 16));
    ml = max(ml, __shfl_xor(ml, 32));
    const int maxlen = __builtin_amdgcn_readfirstlane(ml);

    float a0 = 0.f, a1 = 0.f, a2 = 0.f, a3 = 0.f;
    float a4 = 0.f, a5 = 0.f, a6 = 0.f, a7 = 0.f;

    // ---- raw pack loader: slot j of MY eighth's concatenated stream
    auto load_raw = [&](int j, int& sI, float& wI, int& sO, float& wO) {
        int iIn  = min(ei0 + max(0, min(j, dIn - 1)), neIn - 1);
        int jo   = j - dIn;
        int iOut = min(eo0 + max(0, jo), neOut - 1);
        sI = srcIn[iIn];  wI = ewIn[iIn];
        sO = srcOut[iOut]; wO = ewOut[iOut];
    };

    // ---- convert raw (sI,wI,sO,wO) at slot base p into (rowb, wj)
    auto conv = [&](int p, int sI, float wI, int sO, float wO,
                    int& rowb, float& wj) {
        int j = p + el;
        bool inSeg  = (j < dIn);
        bool anySeg = (j < len);
        int rb = inSeg ? (sI * OUT_CH) : (sO * OUT_CH + Boff);
        rowb = anySeg ? rb : 0;
        wj   = inSeg ? (ci * wI) : (anySeg ? (co * wO) : 0.f);
    };

    // ---- issue the 8 uint4 gathers of one pack (rows broadcast within eighth)
    auto gather = [&](int rowb, uint4 (&u)[8]) {
        int r0 = __shfl(rowb, eb + 0), r1 = __shfl(rowb, eb + 1);
        int r2 = __shfl(rowb, eb + 2), r3 = __shfl(rowb, eb + 3);
        int r4 = __shfl(rowb, eb + 4), r5 = __shfl(rowb, eb + 5);
        int r6 = __shfl(rowb, eb + 6), r7 = __shfl(rowb, eb + 7);
        u[0] = *(const uint4*)(Hq + r0);
        u[1] = *(const uint4*)(Hq + r1);
        u[2] = *(const uint4*)(Hq + r2);
        u[3] = *(const uint4*)(Hq + r3);
        u[4] = *(const uint4*)(Hq + r4);
        u[5] = *(const uint4*)(Hq + r5);
        u[6] = *(const uint4*)(Hq + r6);
        u[7] = *(const uint4*)(Hq + r7);
    };

    // ---- consume one pack: broadcast weights at use time, 128 FMAs
    auto consume = [&](const uint4 (&u)[8], float wj) {
#pragma unroll
        for (int k = 0; k < 8; ++k) {
            float wk = __shfl(wj, eb + k);
            uint4 uk = u[k];
            a0 += wk * bfl(uk.x); a1 += wk * bfh(uk.x);
            a2 += wk * bfl(uk.y); a3 += wk * bfh(uk.y);
            a4 += wk * bfl(uk.z); a5 += wk * bfh(uk.z);
            a6 += wk * bfl(uk.w); a7 += wk * bfh(uk.w);
        }
    };

    int   sIa, sOa, sIb, sOb;
    float wIa, wOa, wIb, wOb;
    uint4 uA[8], uB[8];
    float wjA = 0.f, wjB = 0.f;

    // ---- prologue: fill both pipeline stages
    load_raw(el,     sIa, wIa, sOa, wOa);    // pack offset 0 raws
    load_raw(8 + el, sIb, wIb, sOb, wOb);    // pack offset 8 raws
    {
        int rb; conv(0, sIa, wIa, sOa, wOa, rb, wjA);
        gather(rb, uA);                       // pack 0 gathers in flight
    }
    load_raw(16 + el, sIa, wIa, sOa, wOa);   // pack 16 raws (in flight)
    {
        int rb; conv(8, sIb, wIb, sOb, wOb, rb, wjB);
        gather(rb, uB);                       // pack 8 gathers in flight
    }
    load_raw(24 + el, sIb, wIb, sOb, wOb);   // pack 24 raws (in flight)

    // ---- steady state: consume pack p / p+8, prep pack p+16 / p+24
    for (int p = 0; p < maxlen; p += 16) {
        consume(uA, wjA);                     // pack p
        if (p + 16 < maxlen) {
            int rb; conv(p + 16, sIa, wIa, sOa, wOa, rb, wjA);
            load_raw(p + 32 + el, sIa, wIa, sOa, wOa);
            gather(rb, uA);                   // pack p+16 in flight
        }
        if (p + 8 < maxlen) consume(uB, wjB); // pack p+8
        if (p + 24 < maxlen) {
            int rb; conv(p + 24, sIb, wIb, sOb, wOb, rb, wjB);
            load_raw(p + 40 + el, sIb, wIb, sOb, wOb);
            gather(rb, uB);                   // pack p+24 in flight
        }
    }

    if (valid) {
        float4 o0, o1;
        o0.x = a0 + ci * (bmi[ch8 + 0] + bsi[ch8 + 0]) + co * (bmo[ch8 + 0] + bso[ch8 + 0]);
        o0.y = a1 + ci * (bmi[ch8 + 1] + bsi[ch8 + 1]) + co * (bmo[ch8 + 1] + bso[ch8 + 1]);
        o0.z = a2 + ci * (bmi[ch8 + 2] + bsi[ch8 + 2]) + co * (bmo[ch8 + 2] + bso[ch8 + 2]);
        o0.w = a3 + ci * (bmi[ch8 + 3] + bsi[ch8 + 3]) + co * (bmo[ch8 + 3] + bso[ch8 + 3]);
        o1.x = a4 + ci * (bmi[ch8 + 4] + bsi[ch8 + 4]) + co * (bmo[ch8 + 4] + bso[ch8 + 4]);
        o1.y = a5 + ci * (bmi[ch8 + 5] + bsi[ch8 + 5]) + co * (bmo[ch8 + 5] + bso[ch8 + 5]);
        o1.z = a6 + ci * (bmi[ch8 + 6] + bsi[ch8 + 6]) + co * (bmo[ch8 + 6] + bso[ch8 + 6]);
        o1.w = a7 + ci * (bmi[ch8 + 7] + bsi[ch8 + 7]) + co * (bmo[ch8 + 7] + bso[ch8 + 7]);
        float* ob = out + (long long)t * OUT_CH + ch8;
        *(float4*)ob = o0;
        *(float4*)(ob + 4) = o1;
    }
}

// ---------------------------------------------------------------------------
extern "C" void kernel_launch(void* const* d_in, const int* in_sizes, int n_in,
                              void* d_out, int out_size, void* d_ws, size_t ws_size,
                              hipStream_t stream)
{
    const float* x    = (const float*)d_in[0];
    const float* Wmi  = (const float*)d_in[1];
    const float* Wmo  = (const float*)d_in[2];
    const float* Wsh  = (const float*)d_in[3];
    const float* bmi  = (const float*)d_in[4];
    const float* bmo  = (const float*)d_in[5];
    const float* bsi  = (const float*)d_in[6];
    const float* bso  = (const float*)d_in[7];
    const float* Cin  = (const float*)d_in[8];
    const float* Cout = (const float*)d_in[9];
    const int*   eiIn  = (const int*)d_in[10];
    const float* ewIn  = (const float*)d_in[11];
    const int*   eiOut = (const int*)d_in[12];
    const float* ewOut = (const float*)d_in[13];

    const int n_nodes = in_sizes[0] / IN_CH;   // 100000
    const int neIn  = in_sizes[11];            // 1000000
    const int neOut = in_sizes[13];

    const int* srcIn  = eiIn;                  // edge_index[0]
    const int* tgtIn  = eiIn + neIn;           // edge_index[1] (sorted)
    const int* srcOut = eiOut;
    const int* tgtOut = eiOut + neOut;

    // Workspace layout: Abf|Bbf contiguous (bf16) | rpIn | rpOut | WcT (bf16)
    char* ws = (char*)d_ws;
    size_t NH = (size_t)n_nodes * OUT_CH * sizeof(unsigned short);
    unsigned short* Abf = (unsigned short*)ws;
    unsigned short* Bbf = (unsigned short*)(ws + NH);
    int* rpIn  = (int*)(ws + 2 * NH);
    int* rpOut = rpIn + (n_nodes + 1);
    unsigned short* WcT = (unsigned short*)(rpOut + (n_nodes + 1));

    // 1) rowptrs (edge-parallel diff scan) + combined-weight bf16 pre-pack
    int prep_threads = (neIn + 1) + (neOut + 1) + 2 * OUT_CH * IN_CH;
    prep_kernel<<<(prep_threads + 255) / 256, 256, 0, stream>>>(
        tgtIn, tgtOut, Wmi, Wmo, Wsh, rpIn, rpOut, WcT, n_nodes, neIn, neOut);

    // 2) fused dense transform via MFMA (N=128 GEMM: [A|B] columns)
    int gblocks = (n_nodes + M_TILE - 1) / M_TILE;
    gemm_kernel<<<gblocks, 256, 0, stream>>>(x, WcT, Abf, Bbf, n_nodes);

    // 3) segmented gather-sum + epilogue (pipelined eighth-wave per node)
    int pblocks = (n_nodes + 31) / 32;         // 32 nodes per block
    prop_kernel<<<pblocks, 256, 0, stream>>>(
        Abf, rpIn, rpOut, srcIn, ewIn, srcOut, ewOut,
        bmi, bmo, bsi, bso, Cin, Cout, (float*)d_out, n_nodes, neIn, neOut);
}